// Round 5
// baseline (1359.680 us; speedup 1.0000x reference)
//
#include <hip/hip_runtime.h>
#include <math.h>

#define K_IN 12288
#define HID  1024
#define G4   4096
#define TS   256

typedef unsigned long long u64;
typedef unsigned int u32;
typedef __attribute__((ext_vector_type(4))) float f32x4;
typedef __attribute__((ext_vector_type(16))) float f32x16;
typedef __attribute__((ext_vector_type(8))) _Float16 half8;

// ---------------------------------------------------------------------------
// Kernel 1: partial GEMM via f16-split MFMA.
//   xpartT[ks][j][t] = dot(X[t, kslice], W[j, kslice])   (note: j-major!)
// fp32 inputs are split a = hi + lo (f16 RNE; |lo| <= 2^-12|a|, residual
// 2^-23) and computed as hi*hi + hi*lo + lo*hi with mfma_f32_32x32x16_f16
// (lo*lo <= 2^-24 rel, dropped). Effective precision ~fp32.
// No LDS, no barriers: each lane loads its 8 k-contiguous fp32 per operand
// tile directly from global (lanes l and l+32 jointly cover each 64B line),
// converts in-register, feeds MFMA. Next k-step loads prefetched into regs.
// Wave layout: 4 waves/block, wave (j-sub = w&1, t-sub = w>>1) owns 64x64 =
// 2x2 MFMA tiles of 32x32. Block = 128j x 128t. Grid (TS/128, G4/128, nks).
// C/D mapping (HW-verified, guide m74/m101): col = lane&31 (t, from B
// operand), row = (reg&3) + 8*(reg>>2) + 4*(lane>>5) (j, from A operand).
// Transposed store -> 32 consecutive t per half-wave = 128B coalesced.
// ---------------------------------------------------------------------------
static __device__ __forceinline__ void split8(const f32x4 v0, const f32x4 v1,
                                              half8& hi, half8& lo) {
#pragma unroll
  for (int e = 0; e < 4; ++e) {
    _Float16 h0 = (_Float16)v0[e];
    hi[e] = h0;
    lo[e] = (_Float16)(v0[e] - (float)h0);
    _Float16 h1 = (_Float16)v1[e];
    hi[e + 4] = h1;
    lo[e + 4] = (_Float16)(v1[e] - (float)h1);
  }
}

__global__ __launch_bounds__(256, 2) void xproj_gemm(
    const float* __restrict__ X,     // (256, 12288)
    const float* __restrict__ W,     // (4096, 12288)
    float* __restrict__ xpartT,      // (nks, 4096, 256)  j-major
    int kspan)
{
  const int tid = threadIdx.x;
  const int wave = tid >> 6;
  const int lane = tid & 63;
  const int l31 = lane & 31;
  const int kh = (lane >> 5) * 8;    // k sub-offset within 16

  const int t0 = blockIdx.x * 128 + (wave >> 1) * 64;
  const int j0 = blockIdx.y * 128 + (wave & 1) * 64;
  const int ks = blockIdx.z;
  const int kbeg = ks * kspan;

  const float* wa0 = W + (size_t)(j0 + l31) * K_IN + kbeg + kh;
  const float* wa1 = W + (size_t)(j0 + 32 + l31) * K_IN + kbeg + kh;
  const float* xb0 = X + (size_t)(t0 + l31) * K_IN + kbeg + kh;
  const float* xb1 = X + (size_t)(t0 + 32 + l31) * K_IN + kbeg + kh;

  f32x16 acc[2][2];
#pragma unroll
  for (int mi = 0; mi < 2; ++mi)
#pragma unroll
    for (int ni = 0; ni < 2; ++ni)
#pragma unroll
      for (int e = 0; e < 16; ++e) acc[mi][ni][e] = 0.f;

  // current k-step registers
  f32x4 A0a = *(const f32x4*)(wa0);     f32x4 A0b = *(const f32x4*)(wa0 + 4);
  f32x4 A1a = *(const f32x4*)(wa1);     f32x4 A1b = *(const f32x4*)(wa1 + 4);
  f32x4 B0a = *(const f32x4*)(xb0);     f32x4 B0b = *(const f32x4*)(xb0 + 4);
  f32x4 B1a = *(const f32x4*)(xb1);     f32x4 B1b = *(const f32x4*)(xb1 + 4);

  const int nsteps = kspan >> 4;
  for (int s = 0; s < nsteps; ++s) {
    // prefetch next k-step (re-loads current on last iter; harmless)
    const int koff = (s + 1 < nsteps) ? (s + 1) * 16 : s * 16;
    f32x4 nA0a = *(const f32x4*)(wa0 + koff);
    f32x4 nA0b = *(const f32x4*)(wa0 + koff + 4);
    f32x4 nA1a = *(const f32x4*)(wa1 + koff);
    f32x4 nA1b = *(const f32x4*)(wa1 + koff + 4);
    f32x4 nB0a = *(const f32x4*)(xb0 + koff);
    f32x4 nB0b = *(const f32x4*)(xb0 + koff + 4);
    f32x4 nB1a = *(const f32x4*)(xb1 + koff);
    f32x4 nB1b = *(const f32x4*)(xb1 + koff + 4);

    half8 ah0, al0, ah1, al1, bh0, bl0, bh1, bl1;
    split8(A0a, A0b, ah0, al0);
    split8(A1a, A1b, ah1, al1);
    split8(B0a, B0b, bh0, bl0);
    split8(B1a, B1b, bh1, bl1);

    acc[0][0] = __builtin_amdgcn_mfma_f32_32x32x16_f16(ah0, bh0, acc[0][0], 0, 0, 0);
    acc[0][1] = __builtin_amdgcn_mfma_f32_32x32x16_f16(ah0, bh1, acc[0][1], 0, 0, 0);
    acc[1][0] = __builtin_amdgcn_mfma_f32_32x32x16_f16(ah1, bh0, acc[1][0], 0, 0, 0);
    acc[1][1] = __builtin_amdgcn_mfma_f32_32x32x16_f16(ah1, bh1, acc[1][1], 0, 0, 0);
    acc[0][0] = __builtin_amdgcn_mfma_f32_32x32x16_f16(ah0, bl0, acc[0][0], 0, 0, 0);
    acc[0][1] = __builtin_amdgcn_mfma_f32_32x32x16_f16(ah0, bl1, acc[0][1], 0, 0, 0);
    acc[1][0] = __builtin_amdgcn_mfma_f32_32x32x16_f16(ah1, bl0, acc[1][0], 0, 0, 0);
    acc[1][1] = __builtin_amdgcn_mfma_f32_32x32x16_f16(ah1, bl1, acc[1][1], 0, 0, 0);
    acc[0][0] = __builtin_amdgcn_mfma_f32_32x32x16_f16(al0, bh0, acc[0][0], 0, 0, 0);
    acc[0][1] = __builtin_amdgcn_mfma_f32_32x32x16_f16(al0, bh1, acc[0][1], 0, 0, 0);
    acc[1][0] = __builtin_amdgcn_mfma_f32_32x32x16_f16(al1, bh0, acc[1][0], 0, 0, 0);
    acc[1][1] = __builtin_amdgcn_mfma_f32_32x32x16_f16(al1, bh1, acc[1][1], 0, 0, 0);

    A0a = nA0a; A0b = nA0b; A1a = nA1a; A1b = nA1b;
    B0a = nB0a; B0b = nB0b; B1a = nB1a; B1b = nB1b;
  }

  float* outp = xpartT + (size_t)ks * G4 * TS;
#pragma unroll
  for (int mi = 0; mi < 2; ++mi)
#pragma unroll
    for (int ni = 0; ni < 2; ++ni)
#pragma unroll
      for (int rg = 0; rg < 16; ++rg) {
        const int j = j0 + mi * 32 + (rg & 3) + 8 * (rg >> 2) + 4 * (lane >> 5);
        const int t = t0 + ni * 32 + l31;
        outp[(size_t)j * TS + t] = acc[mi][ni][rg];
      }
}

// ---------------------------------------------------------------------------
// Kernel 1b: xprojT[j][t] = sum_ks xpartT[ks][j][t] + b_ih[j] + b_hh[j]
// (j-major layout; 4 consecutive t per thread share one j)
// ---------------------------------------------------------------------------
__global__ __launch_bounds__(256) void xproj_reduce(
    const float* __restrict__ xpartT, int nks,
    const float* __restrict__ b_ih, const float* __restrict__ b_hh,
    float* __restrict__ xprojT)
{
  const int idx = (blockIdx.x * 256 + threadIdx.x) * 4;  // over G4*TS elems
  float4 s = *(const float4*)(xpartT + idx);
  for (int ks = 1; ks < nks; ++ks) {
    float4 p = *(const float4*)(xpartT + (size_t)ks * G4 * TS + idx);
    s.x += p.x; s.y += p.y; s.z += p.z; s.w += p.w;
  }
  const int j = idx >> 8;  // TS = 256
  const float bias = b_ih[j] + b_hh[j];
  s.x += bias; s.y += bias; s.z += bias; s.w += bias;
  *(float4*)(xprojT + idx) = s;
}

// ---------------------------------------------------------------------------
// Kernel 2: persistent LSTM scan. 128 WGs x 256 threads.
// = round-2's remapped structure (HW-passed) + round-4's receive (HW-passed).
// Row mapping: r = tid>>3, gate = r&3, unit = r>>2 -> a unit's 4 gates live
// in one half-wave: gate exchange via 4 __shfl (no B3 barrier, no gates_lds),
// c replicated in registers per half-wave, publish straight from the wave
// (no tid<8 serial tail). One __syncthreads per step (h_lds double-buffered;
// buffer reused at t+2 is protected by the barrier at t+1).
// Receive: spin on slot 0 only (1 load/thread/iter — proven poll rate; the
// 4-wide poll congested the fabric, r1: 687->938), then batch-load slots 1-3
// (published by the same wave64 store -> verify passes first try).
// Overwrite safety: every WG reads all 1024 slots each step -> tag t -> t+2
// overwrite only after all WGs consumed t; stale tags from prior runs (255/
// 256/0xAA) never match expected tags [1,256].
// ---------------------------------------------------------------------------
#define NWG 128
#define UPW 8

__global__ __launch_bounds__(256, 1) void lstm_scan(
    const float* __restrict__ W_hh,    // (4096, 1024)
    const float* __restrict__ xprojT,  // (4096, 256)  j-major
    u64* __restrict__ hmsg)            // (2, 1024) packed {tag,val}
{
  const int tid = threadIdx.x;
  const int w = blockIdx.x;
  const int u0 = w * UPW;
  const int r = tid >> 3;            // 0..31 local row
  const int sub = tid & 7;           // 8 lanes per row, 128 h-elems each
  const int gate = r & 3;            // 0..3  (i,f,g,o)
  const int hrow = gate * HID + u0 + (r >> 2);
  const int lane = tid & 63;

  __shared__ __align__(16) float h_lds[2][8 * 132];

  // my 128-float W_hh segment in registers
  float4 Wreg[32];
  const float4* wp = (const float4*)(W_hh + (size_t)hrow * HID + sub * 128);
#pragma unroll
  for (int i = 0; i < 32; ++i) Wreg[i] = wp[i];

  const float* xrow = xprojT + (size_t)hrow * TS;
  float c_reg = 0.f;  // identical across each half-wave

  for (int t = 0; t < TS; ++t) {
    // prefetch my xproj element (sequential in t -> L1-resident line)
    float xp = xrow[t];

    float p0 = 0.f, p1 = 0.f, p2 = 0.f, p3 = 0.f;
    if (t > 0) {
      const u64* slot = hmsg + (t & 1) * HID;
      const u32 tt = (u32)t;
      u64 m0, m1, m2, m3;
      // spin on slot 0 only
      do {
        m0 = __hip_atomic_load(&slot[tid * 4 + 0], __ATOMIC_RELAXED,
                               __HIP_MEMORY_SCOPE_AGENT);
      } while ((u32)(m0 >> 32) != tt);
      // slots 1-3: batch issue, then verify (first-try pass in common case)
      m1 = __hip_atomic_load(&slot[tid * 4 + 1], __ATOMIC_RELAXED,
                             __HIP_MEMORY_SCOPE_AGENT);
      m2 = __hip_atomic_load(&slot[tid * 4 + 2], __ATOMIC_RELAXED,
                             __HIP_MEMORY_SCOPE_AGENT);
      m3 = __hip_atomic_load(&slot[tid * 4 + 3], __ATOMIC_RELAXED,
                             __HIP_MEMORY_SCOPE_AGENT);
      while ((u32)(m1 >> 32) != tt)
        m1 = __hip_atomic_load(&slot[tid * 4 + 1], __ATOMIC_RELAXED,
                               __HIP_MEMORY_SCOPE_AGENT);
      while ((u32)(m2 >> 32) != tt)
        m2 = __hip_atomic_load(&slot[tid * 4 + 2], __ATOMIC_RELAXED,
                               __HIP_MEMORY_SCOPE_AGENT);
      while ((u32)(m3 >> 32) != tt)
        m3 = __hip_atomic_load(&slot[tid * 4 + 3], __ATOMIC_RELAXED,
                               __HIP_MEMORY_SCOPE_AGENT);
      float* hb = h_lds[t & 1];
      const int st = tid >> 5;
      const int off = (tid & 31) * 4;
      hb[st * 132 + off + 0] = __uint_as_float((u32)m0);
      hb[st * 132 + off + 1] = __uint_as_float((u32)m1);
      hb[st * 132 + off + 2] = __uint_as_float((u32)m2);
      hb[st * 132 + off + 3] = __uint_as_float((u32)m3);
      __syncthreads();  // h_lds[t&1] ready (also fences t+2 buffer reuse)
      const float4* hl = (const float4*)(hb + sub * 132);
#pragma unroll
      for (int i = 0; i < 32; i += 4) {
        float4 h4;
        h4 = hl[i + 0];
        p0 += Wreg[i + 0].x * h4.x + Wreg[i + 0].y * h4.y +
              Wreg[i + 0].z * h4.z + Wreg[i + 0].w * h4.w;
        h4 = hl[i + 1];
        p1 += Wreg[i + 1].x * h4.x + Wreg[i + 1].y * h4.y +
              Wreg[i + 1].z * h4.z + Wreg[i + 1].w * h4.w;
        h4 = hl[i + 2];
        p2 += Wreg[i + 2].x * h4.x + Wreg[i + 2].y * h4.y +
              Wreg[i + 2].z * h4.z + Wreg[i + 2].w * h4.w;
        h4 = hl[i + 3];
        p3 += Wreg[i + 3].x * h4.x + Wreg[i + 3].y * h4.y +
              Wreg[i + 3].z * h4.z + Wreg[i + 3].w * h4.w;
      }
    }
    float partial = (p0 + p1) + (p2 + p3);
    // reduce across the 8 sub-lanes of this row (same wave)
    partial += __shfl_xor(partial, 1, 64);
    partial += __shfl_xor(partial, 2, 64);
    partial += __shfl_xor(partial, 4, 64);
    float gsum = partial + xp;
    float act = (gate == 2) ? tanhf(gsum) : 1.f / (1.f + expf(-gsum));
    // gather this half-wave's unit gates: lanes base+{0,8,16,24} = i,f,g,o
    const int base = lane & 32;
    float iv = __shfl(act, base + 0, 64);
    float fv = __shfl(act, base + 8, 64);
    float gv = __shfl(act, base + 16, 64);
    float ov = __shfl(act, base + 24, 64);
    c_reg = fv * c_reg + iv * gv;
    float hnew = ov * tanhf(c_reg);
    if ((lane & 31) == 0) {
      u64 msg = ((u64)(u32)(t + 1) << 32) | (u64)__float_as_uint(hnew);
      __hip_atomic_store(&hmsg[((t + 1) & 1) * HID + u0 + (tid >> 5)], msg,
                         __ATOMIC_RELAXED, __HIP_MEMORY_SCOPE_AGENT);
    }
    // no trailing barrier: next step's barrier protects LDS buffer reuse
  }
}

// ---------------------------------------------------------------------------
// Kernel 3: out[j] = dot(fc_w[j,:], h_T) + fc_b[j].  h_T packed in hmsg slot 0
// (tag 256, step 256 is even) — extract low 32 bits.
// ---------------------------------------------------------------------------
__global__ __launch_bounds__(256) void fc_kernel(
    const float* __restrict__ fc_w,  // (12288, 1024)
    const float* __restrict__ fc_b,  // (12288)
    const u64* __restrict__ hmsg,    // h_T packed at slot 0
    float* __restrict__ out)         // (12288)
{
  __shared__ float h_s[HID];
  const int tid = threadIdx.x;
  for (int k = tid; k < HID; k += 256)
    h_s[k] = __uint_as_float((u32)hmsg[k]);
  __syncthreads();
  const int r = tid >> 2;    // 0..63
  const int sub = tid & 3;   // 256 elems each
  const int j = blockIdx.x * 64 + r;
  const float4* wrow = (const float4*)(fc_w + (size_t)j * HID + sub * 256);
  const float4* hp = (const float4*)(h_s + sub * 256);
  float s = 0.f;
#pragma unroll
  for (int i = 0; i < 64; ++i) {
    float4 wv = wrow[i];
    float4 hv = hp[i];
    s += wv.x * hv.x + wv.y * hv.y + wv.z * hv.z + wv.w * hv.w;
  }
  s += __shfl_xor(s, 1, 64);
  s += __shfl_xor(s, 2, 64);
  if (sub == 0) out[j] = s + fc_b[j];
}

// ---------------------------------------------------------------------------
extern "C" void kernel_launch(void* const* d_in, const int* in_sizes, int n_in,
                              void* d_out, int out_size, void* d_ws, size_t ws_size,
                              hipStream_t stream) {
  const float* frames = (const float*)d_in[0];  // (256,3,64,64)
  const float* W_ih   = (const float*)d_in[1];  // (4096,12288)
  const float* W_hh   = (const float*)d_in[2];  // (4096,1024)
  const float* b_ih   = (const float*)d_in[3];  // (4096)
  const float* b_hh   = (const float*)d_in[4];  // (4096)
  const float* fc_w   = (const float*)d_in[5];  // (12288,1024)
  const float* fc_b   = (const float*)d_in[6];  // (12288)
  float* out = (float*)d_out;

  const size_t XPROJ_BYTES = (size_t)TS * G4 * 4;  // 4 MB
  int nks = 1;
  if (ws_size >= XPROJ_BYTES * 9 + (1 << 20)) nks = 8;
  else if (ws_size >= XPROJ_BYTES * 5 + (1 << 20)) nks = 4;
  else if (ws_size >= XPROJ_BYTES * 3 + (1 << 20)) nks = 2;

  char* ws = (char*)d_ws;
  float* xprojT = (float*)ws;                                 // 4 MB (j-major)
  float* xpartT = (float*)(ws + XPROJ_BYTES);                 // nks * 4 MB
  u64*   hmsg   = (u64*)(ws + XPROJ_BYTES * (1 + nks));       // 16 KB
  // hmsg deliberately NOT initialized: 0xAA poison tag never matches [1,256].

  const int kspan = K_IN / nks;
  xproj_gemm<<<dim3(TS / 128, G4 / 128, nks), 256, 0, stream>>>(frames, W_ih, xpartT, kspan);
  xproj_reduce<<<dim3(G4 * TS / 4 / 256), 256, 0, stream>>>(xpartT, nks, b_ih, b_hh, xprojT);
  lstm_scan<<<dim3(NWG), 256, 0, stream>>>(W_hh, xprojT, hmsg);
  fc_kernel<<<dim3(12288 / 64), 256, 0, stream>>>(fc_w, fc_b, hmsg, out);
}

// Round 8
// 1022.727 us; speedup vs baseline: 1.3295x; 1.3295x over previous
//
#include <hip/hip_runtime.h>
#include <math.h>

#define K_IN 12288
#define HID  1024
#define G4   4096
#define TS   256

typedef unsigned long long u64;
typedef unsigned int u32;
typedef __attribute__((ext_vector_type(4))) float f32x4;
typedef __attribute__((ext_vector_type(16))) float f32x16;
typedef __attribute__((ext_vector_type(8))) _Float16 half8;
typedef __attribute__((ext_vector_type(4))) _Float16 half4;

// ---------------------------------------------------------------------------
// Kernel 1: partial GEMM via f16-split MFMA with LDS-staged, once-per-element
// conversion.   xpartT[ks][j][t] = dot(X[t,kslice], W[j,kslice])  (j-major)
//
// fp32 split a = hi + lo (f16 RNE), product = hh + hl + lh via
// mfma_f32_32x32x16_f16 (al*bl <= 2^-22 rel, dropped). Validated in r5
// (passed, absmax unchanged vs fp32).
//
//  - block = 128j x 256t(full) x BK=16, 8 waves; W converted ONCE per
//    element (no t-redundancy), X redundancy only x32 (12MB matrix).
//  - staging: coalesced f32 loads (4 lanes = 64B line fully consumed),
//    in-register split, f16 hi/lo written to LDS as [kh][row][8 f16=16B].
//  - fragment read = 32 consecutive lanes x consecutive 16B -> conflict-free
//    ds_read_b128; one b128 per fragment.
//  - LDS arrays __align__(16): all half8 LDS ops are b128 — natural f16
//    alignment (2B) does NOT guarantee the 16B base alignment they require
//    (misaligned b128 DS access = fault, the one candidate found for the
//    r6/r7 container deaths).
// Per wave per k16: 12 MFMA (96cy) ~ 8 ds_read (96cy) ~ 36 VALU (72cy).
// C/D mapping (HW-validated r5): col = lane&31 = t, row = (rg&3)+8*(rg>>2)
// +4*kh = j; transposed store -> 128B-coalesced.
// ---------------------------------------------------------------------------
__global__ __launch_bounds__(512, 2) void xproj_gemm(
    const float* __restrict__ X,     // (256, 12288)
    const float* __restrict__ W,     // (4096, 12288)
    float* __restrict__ xpartT,      // (nks, 4096, 256)  j-major
    int kspan)
{
  __shared__ __align__(16) _Float16 Ahi[2][128][8];  // [kh][j-local][8 f16]
  __shared__ __align__(16) _Float16 Alo[2][128][8];
  __shared__ __align__(16) _Float16 Bhi[2][256][8];  // [kh][t][8 f16]
  __shared__ __align__(16) _Float16 Blo[2][256][8];

  const int tid = threadIdx.x;
  const int wave = tid >> 6;          // 0..7
  const int lane = tid & 63;
  const int l31 = lane & 31;
  const int kh = lane >> 5;           // 0/1: k-half of the fragment

  const int j0 = blockIdx.x * 128;
  const int ks = blockIdx.y;
  const int kbeg = ks * kspan;

  const int jw = (wave & 1) * 64;     // wave j-sub (0/64)
  const int tw = (wave >> 1) * 64;    // wave t-sub (0/64/128/192)

  // staging mapping (coalesced: 4 lanes cover one 64B row-chunk)
  const int wrow = tid >> 2;          // 0..127
  const int wkq  = tid & 3;           // float4 within 16 k
  const int xrow = tid >> 1;          // 0..255
  const int xkq  = tid & 1;           // 8-float half within 16 k

  const float* wsrc = W + (size_t)(j0 + wrow) * K_IN + kbeg + wkq * 4;
  const float* xsrc = X + (size_t)xrow * K_IN + kbeg + xkq * 8;

  f32x16 acc[2][2];
#pragma unroll
  for (int mi = 0; mi < 2; ++mi)
#pragma unroll
    for (int ni = 0; ni < 2; ++ni)
#pragma unroll
      for (int e = 0; e < 16; ++e) acc[mi][ni][e] = 0.f;

  // prologue: first k-tile into registers
  f32x4 wv  = *(const f32x4*)wsrc;
  f32x4 xv0 = *(const f32x4*)xsrc;
  f32x4 xv1 = *(const f32x4*)(xsrc + 4);

  const int nsteps = kspan >> 4;
  for (int s = 0; s < nsteps; ++s) {
    // convert current regs -> f16 hi/lo -> LDS
    {
      half4 hw, lw;
#pragma unroll
      for (int e = 0; e < 4; ++e) {
        _Float16 h = (_Float16)wv[e];
        hw[e] = h;
        lw[e] = (_Float16)(wv[e] - (float)h);
      }
      *(half4*)&Ahi[wkq >> 1][wrow][(wkq & 1) * 4] = hw;
      *(half4*)&Alo[wkq >> 1][wrow][(wkq & 1) * 4] = lw;
      half8 hx, lx;
#pragma unroll
      for (int e = 0; e < 4; ++e) {
        _Float16 h0 = (_Float16)xv0[e];
        hx[e] = h0;
        lx[e] = (_Float16)(xv0[e] - (float)h0);
        _Float16 h1 = (_Float16)xv1[e];
        hx[e + 4] = h1;
        lx[e + 4] = (_Float16)(xv1[e] - (float)h1);
      }
      *(half8*)&Bhi[xkq][xrow][0] = hx;
      *(half8*)&Blo[xkq][xrow][0] = lx;
    }
    __syncthreads();  // staged tile visible

    // prefetch next k-tile into registers (hides under frags+MFMA)
    if (s + 1 < nsteps) {
      const int ko = (s + 1) * 16;
      wv  = *(const f32x4*)(wsrc + ko);
      xv0 = *(const f32x4*)(xsrc + ko);
      xv1 = *(const f32x4*)(xsrc + ko + 4);
    }

    // fragments: conflict-free b128 reads
    half8 aH[2], aL[2], bH[2], bL[2];
#pragma unroll
    for (int mi = 0; mi < 2; ++mi) {
      aH[mi] = *(const half8*)&Ahi[kh][jw + mi * 32 + l31][0];
      aL[mi] = *(const half8*)&Alo[kh][jw + mi * 32 + l31][0];
    }
#pragma unroll
    for (int ni = 0; ni < 2; ++ni) {
      bH[ni] = *(const half8*)&Bhi[kh][tw + ni * 32 + l31][0];
      bL[ni] = *(const half8*)&Blo[kh][tw + ni * 32 + l31][0];
    }

    acc[0][0] = __builtin_amdgcn_mfma_f32_32x32x16_f16(aH[0], bH[0], acc[0][0], 0, 0, 0);
    acc[0][1] = __builtin_amdgcn_mfma_f32_32x32x16_f16(aH[0], bH[1], acc[0][1], 0, 0, 0);
    acc[1][0] = __builtin_amdgcn_mfma_f32_32x32x16_f16(aH[1], bH[0], acc[1][0], 0, 0, 0);
    acc[1][1] = __builtin_amdgcn_mfma_f32_32x32x16_f16(aH[1], bH[1], acc[1][1], 0, 0, 0);
    acc[0][0] = __builtin_amdgcn_mfma_f32_32x32x16_f16(aH[0], bL[0], acc[0][0], 0, 0, 0);
    acc[0][1] = __builtin_amdgcn_mfma_f32_32x32x16_f16(aH[0], bL[1], acc[0][1], 0, 0, 0);
    acc[1][0] = __builtin_amdgcn_mfma_f32_32x32x16_f16(aH[1], bL[0], acc[1][0], 0, 0, 0);
    acc[1][1] = __builtin_amdgcn_mfma_f32_32x32x16_f16(aH[1], bL[1], acc[1][1], 0, 0, 0);
    acc[0][0] = __builtin_amdgcn_mfma_f32_32x32x16_f16(aL[0], bH[0], acc[0][0], 0, 0, 0);
    acc[0][1] = __builtin_amdgcn_mfma_f32_32x32x16_f16(aL[0], bH[1], acc[0][1], 0, 0, 0);
    acc[1][0] = __builtin_amdgcn_mfma_f32_32x32x16_f16(aL[1], bH[0], acc[1][0], 0, 0, 0);
    acc[1][1] = __builtin_amdgcn_mfma_f32_32x32x16_f16(aL[1], bH[1], acc[1][1], 0, 0, 0);

    __syncthreads();  // frag reads done before next overwrite
  }

  float* outp = xpartT + (size_t)ks * G4 * TS;
#pragma unroll
  for (int mi = 0; mi < 2; ++mi)
#pragma unroll
    for (int ni = 0; ni < 2; ++ni)
#pragma unroll
      for (int rg = 0; rg < 16; ++rg) {
        const int j = j0 + jw + mi * 32 + (rg & 3) + 8 * (rg >> 2) + 4 * kh;
        const int t = tw + ni * 32 + l31;
        outp[(size_t)j * TS + t] = acc[mi][ni][rg];
      }
}

// ---------------------------------------------------------------------------
// Kernel 1b: xprojT[j][t] = sum_ks xpartT[ks][j][t] + b_ih[j] + b_hh[j]
// ---------------------------------------------------------------------------
__global__ __launch_bounds__(256) void xproj_reduce(
    const float* __restrict__ xpartT, int nks,
    const float* __restrict__ b_ih, const float* __restrict__ b_hh,
    float* __restrict__ xprojT)
{
  const int idx = (blockIdx.x * 256 + threadIdx.x) * 4;  // over G4*TS elems
  float4 s = *(const float4*)(xpartT + idx);
  for (int ks = 1; ks < nks; ++ks) {
    float4 p = *(const float4*)(xpartT + (size_t)ks * G4 * TS + idx);
    s.x += p.x; s.y += p.y; s.z += p.z; s.w += p.w;
  }
  const int j = idx >> 8;  // TS = 256
  const float bias = b_ih[j] + b_hh[j];
  s.x += bias; s.y += bias; s.z += bias; s.w += bias;
  *(float4*)(xprojT + idx) = s;
}

// ---------------------------------------------------------------------------
// Kernel 2: persistent LSTM scan — EXACT round-4 structure (proven 630 µs):
// single-wave publish (tid<8, one 64B line, one visibility event — r5's
// 4-wave scattered publish regressed 630->855), slot-0-only spin + batch
// verify, B1/B2/B3 barriers, gates_lds, c_lds. Only change vs r4: xproj is
// j-major (xprojT[hrow][t]) — sequential t reads stay in one L1 line for
// 16 steps.
// ---------------------------------------------------------------------------
#define NWG 128
#define UPW 8

__global__ __launch_bounds__(256, 1) void lstm_scan(
    const float* __restrict__ W_hh,    // (4096, 1024)
    const float* __restrict__ xprojT,  // (4096, 256)  j-major
    u64* __restrict__ hmsg)            // (2, 1024) packed {tag,val}
{
  const int tid = threadIdx.x;
  const int w = blockIdx.x;
  const int u0 = w * UPW;
  const int r = tid >> 3;            // 0..31 local row
  const int sub = tid & 7;           // 8 lanes per row, 128 elems each
  const int gate = r >> 3;           // 0..3
  const int uu = r & 7;              // 0..7
  const int hrow = gate * HID + u0 + uu;

  __shared__ __align__(16) float h_lds[8 * 132];
  __shared__ float gates_lds[32];
  __shared__ float c_lds[UPW];

  // my 128-float W_hh segment in registers
  float4 Wreg[32];
  const float4* wp = (const float4*)(W_hh + (size_t)hrow * HID + sub * 128);
#pragma unroll
  for (int i = 0; i < 32; ++i) Wreg[i] = wp[i];

  const float* xrow = xprojT + (size_t)hrow * TS;

  if (tid < UPW) c_lds[tid] = 0.f;
  __syncthreads();

  for (int t = 0; t < TS; ++t) {
    // prefetch my xproj element early (hides L1/L2 latency behind the spin)
    float xp = 0.f;
    if (sub == 0) xp = xrow[t];

    float partial = 0.f;
    if (t > 0) {
      const u64* slot = hmsg + (t & 1) * HID;
      const u32 tt = (u32)t;
      u64 m0, m1, m2, m3;
      // spin on slot 0 only (1 load/thread/iter — proven-safe poll rate)
      do {
        m0 = __hip_atomic_load(&slot[tid * 4 + 0], __ATOMIC_RELAXED,
                               __HIP_MEMORY_SCOPE_AGENT);
      } while ((u32)(m0 >> 32) != tt);
      // slots 1-3: batch issue (one round-trip), then verify
      m1 = __hip_atomic_load(&slot[tid * 4 + 1], __ATOMIC_RELAXED,
                             __HIP_MEMORY_SCOPE_AGENT);
      m2 = __hip_atomic_load(&slot[tid * 4 + 2], __ATOMIC_RELAXED,
                             __HIP_MEMORY_SCOPE_AGENT);
      m3 = __hip_atomic_load(&slot[tid * 4 + 3], __ATOMIC_RELAXED,
                             __HIP_MEMORY_SCOPE_AGENT);
      while ((u32)(m1 >> 32) != tt)
        m1 = __hip_atomic_load(&slot[tid * 4 + 1], __ATOMIC_RELAXED,
                               __HIP_MEMORY_SCOPE_AGENT);
      while ((u32)(m2 >> 32) != tt)
        m2 = __hip_atomic_load(&slot[tid * 4 + 2], __ATOMIC_RELAXED,
                               __HIP_MEMORY_SCOPE_AGENT);
      while ((u32)(m3 >> 32) != tt)
        m3 = __hip_atomic_load(&slot[tid * 4 + 3], __ATOMIC_RELAXED,
                               __HIP_MEMORY_SCOPE_AGENT);
      __syncthreads();  // B1: prev step's h_lds readers done
      const int st = tid >> 5;
      const int off = (tid & 31) * 4;
      h_lds[st * 132 + off + 0] = __uint_as_float((u32)m0);
      h_lds[st * 132 + off + 1] = __uint_as_float((u32)m1);
      h_lds[st * 132 + off + 2] = __uint_as_float((u32)m2);
      h_lds[st * 132 + off + 3] = __uint_as_float((u32)m3);
      __syncthreads();  // B2: h_lds ready
      const float4* hl = (const float4*)(h_lds + sub * 132);
#pragma unroll
      for (int i = 0; i < 32; ++i) {
        float4 h4 = hl[i];
        partial += Wreg[i].x * h4.x + Wreg[i].y * h4.y +
                   Wreg[i].z * h4.z + Wreg[i].w * h4.w;
      }
    }
    // reduce across the 8 sub-lanes of this row (same wave)
    partial += __shfl_xor(partial, 1, 64);
    partial += __shfl_xor(partial, 2, 64);
    partial += __shfl_xor(partial, 4, 64);
    if (sub == 0) {
      float gsum = partial + xp;
      float act = (gate == 2) ? tanhf(gsum) : 1.f / (1.f + expf(-gsum));
      gates_lds[gate * 8 + uu] = act;
    }
    __syncthreads();  // B3: gates ready
    if (tid < UPW) {
      float iv = gates_lds[0 * 8 + tid];
      float fv = gates_lds[1 * 8 + tid];
      float gv = gates_lds[2 * 8 + tid];
      float ov = gates_lds[3 * 8 + tid];
      float c = fv * c_lds[tid] + iv * gv;
      c_lds[tid] = c;
      float hnew = ov * tanhf(c);
      u64 msg = ((u64)(u32)(t + 1) << 32) | (u64)__float_as_uint(hnew);
      __hip_atomic_store(&hmsg[((t + 1) & 1) * HID + u0 + tid], msg,
                         __ATOMIC_RELAXED, __HIP_MEMORY_SCOPE_AGENT);
    }
    // no trailing barrier needed: B1/B3 of the next iteration protect LDS
  }
}

// ---------------------------------------------------------------------------
// Kernel 3: out[j] = dot(fc_w[j,:], h_T) + fc_b[j].
// ---------------------------------------------------------------------------
__global__ __launch_bounds__(256) void fc_kernel(
    const float* __restrict__ fc_w,  // (12288, 1024)
    const float* __restrict__ fc_b,  // (12288)
    const u64* __restrict__ hmsg,    // h_T packed at slot 0
    float* __restrict__ out)         // (12288)
{
  __shared__ float h_s[HID];
  const int tid = threadIdx.x;
  for (int k = tid; k < HID; k += 256)
    h_s[k] = __uint_as_float((u32)hmsg[k]);
  __syncthreads();
  const int r = tid >> 2;    // 0..63
  const int sub = tid & 3;   // 256 elems each
  const int j = blockIdx.x * 64 + r;
  const float4* wrow = (const float4*)(fc_w + (size_t)j * HID + sub * 256);
  const float4* hp = (const float4*)(h_s + sub * 256);
  float s = 0.f;
#pragma unroll
  for (int i = 0; i < 64; ++i) {
    float4 wv = wrow[i];
    float4 hv = hp[i];
    s += wv.x * hv.x + wv.y * hv.y + wv.z * hv.z + wv.w * hv.w;
  }
  s += __shfl_xor(s, 1, 64);
  s += __shfl_xor(s, 2, 64);
  if (sub == 0) out[j] = s + fc_b[j];
}

// ---------------------------------------------------------------------------
extern "C" void kernel_launch(void* const* d_in, const int* in_sizes, int n_in,
                              void* d_out, int out_size, void* d_ws, size_t ws_size,
                              hipStream_t stream) {
  const float* frames = (const float*)d_in[0];  // (256,3,64,64)
  const float* W_ih   = (const float*)d_in[1];  // (4096,12288)
  const float* W_hh   = (const float*)d_in[2];  // (4096,1024)
  const float* b_ih   = (const float*)d_in[3];  // (4096)
  const float* b_hh   = (const float*)d_in[4];  // (4096)
  const float* fc_w   = (const float*)d_in[5];  // (12288,1024)
  const float* fc_b   = (const float*)d_in[6];  // (12288)
  float* out = (float*)d_out;

  const size_t XPROJ_BYTES = (size_t)TS * G4 * 4;  // 4 MB
  int nks = 1;
  if (ws_size >= XPROJ_BYTES * 9 + (1 << 20)) nks = 8;
  else if (ws_size >= XPROJ_BYTES * 5 + (1 << 20)) nks = 4;
  else if (ws_size >= XPROJ_BYTES * 3 + (1 << 20)) nks = 2;

  char* ws = (char*)d_ws;
  float* xprojT = (float*)ws;                                 // 4 MB (j-major)
  float* xpartT = (float*)(ws + XPROJ_BYTES);                 // nks * 4 MB
  u64*   hmsg   = (u64*)(ws + XPROJ_BYTES * (1 + nks));       // 16 KB
  // hmsg deliberately NOT initialized: 0xAA poison tag never matches [1,256].

  const int kspan = K_IN / nks;
  xproj_gemm<<<dim3(G4 / 128, nks), 512, 0, stream>>>(frames, W_ih, xpartT, kspan);
  xproj_reduce<<<dim3(G4 * TS / 4 / 256), 256, 0, stream>>>(xpartT, nks, b_ih, b_hh, xprojT);
  lstm_scan<<<dim3(NWG), 256, 0, stream>>>(W_hh, xprojT, hmsg);
  fc_kernel<<<dim3(12288 / 64), 256, 0, stream>>>(fc_w, fc_b, hmsg, out);
}